// Round 5
// baseline (252.193 us; speedup 1.0000x reference)
//
#include <hip/hip_runtime.h>
#include <math.h>
#include <stdint.h>

#define Bn 8
#define Nn 2048
#define Cn 128
#define CP 144          // padded cols: 128 h-cols + w-col(=128) + 15 zero cols
#define NKB (Nn / 32)   // 64 k-blocks of 32

typedef _Float16 f16x8 __attribute__((ext_vector_type(8)));
typedef _Float16 f16x2 __attribute__((ext_vector_type(2)));
typedef __fp16   fp16x2 __attribute__((ext_vector_type(2)));
typedef float    f32x4 __attribute__((ext_vector_type(4)));

__device__ __forceinline__ void dma16(const void* g, void* l) {
    __builtin_amdgcn_global_load_lds((const __attribute__((address_space(1))) uint32_t*)g,
                                     (__attribute__((address_space(3))) uint32_t*)l,
                                     16, 0, 0);
}

// ---------------------------------------------------------------------------
// rows_kernel: per 64-row chunk: v[c]=Ww^T·aw2, b2=Wb·aw2 (L2-hot recompute),
// w=exp(h·v+b2); writes hWt[b][kb][cp][ks] = f16(w_j*h[j][cp]) for cp<128,
// f16(w_j) at cp=128, 0 for cp 129..143.  j = kb*32+ks.
// grid = 256 blocks (b=bid&7: XCD-local), 256 threads.
// ---------------------------------------------------------------------------
__global__ __launch_bounds__(256) void rows_kernel(const float* __restrict__ h,
                                                   const float* __restrict__ Ww,
                                                   const float* __restrict__ Wb,
                                                   const float* __restrict__ aw,
                                                   _Float16* __restrict__ hWt) {
    __shared__ float tile[64][132];
    __shared__ float vsh[128];
    __shared__ float vpart[128];
    __shared__ float wsh[64];
    __shared__ float b2sh;

    int bid = blockIdx.x;
    int b   = bid & 7;
    int n0  = (bid >> 3) << 6;
    int tid = threadIdx.x;

    {   // v partials
        int c = tid & 127, half = tid >> 7;
        float acc = 0.f;
#pragma unroll
        for (int dd = 0; dd < 64; ++dd) {
            int d = half * 64 + dd;
            acc += Ww[d * Cn + c] * aw[Cn + d];
        }
        if (half) vpart[c] = acc; else vsh[c] = acc;
    }
    if (tid < 64) {                      // b2 = Wb·aw2
        float b2p = Wb[tid] * aw[Cn + tid] + Wb[tid + 64] * aw[Cn + tid + 64];
        b2p += __shfl_xor(b2p, 32, 64);
        b2p += __shfl_xor(b2p, 16, 64);
        b2p += __shfl_xor(b2p, 8, 64);
        b2p += __shfl_xor(b2p, 4, 64);
        b2p += __shfl_xor(b2p, 2, 64);
        b2p += __shfl_xor(b2p, 1, 64);
        if (tid == 0) b2sh = b2p;
    }
    {   // stage 64x128 h tile, coalesced float4
        int r = tid >> 2, qq = tid & 3;
        const float4* rowp = (const float4*)(h + (size_t)(b * Nn + n0 + r) * Cn);
#pragma unroll
        for (int i = 0; i < 8; ++i) {
            int f4 = i * 4 + qq;
            *(float4*)&tile[r][f4 * 4] = rowp[f4];
        }
    }
    __syncthreads();

    {   // w = exp(h·v + b2): 4 threads/row
        int r = tid >> 2, pp = tid & 3;
        float acc = 0.f;
#pragma unroll
        for (int ii = 0; ii < 32; ++ii) {
            int i = pp * 32 + ii;
            acc += tile[r][i] * (vsh[i] + vpart[i]);
        }
        acc += __shfl_xor(acc, 1, 64);
        acc += __shfl_xor(acc, 2, 64);
        if (pp == 0) wsh[r] = expf(acc + b2sh);
    }
    __syncthreads();

    // hWt stores: 2 kb × 144 cp × 16 pairs = 4608 f16x2 / 256 thr = 18 each
    _Float16* hWb = hWt + ((size_t)(b * NKB + (n0 >> 5)) * CP) * 32;
#pragma unroll
    for (int i = 0; i < 18; ++i) {
        int idx = tid + 256 * i;         // 0..4607
        int cp  = idx >> 5;              // 0..143
        int rem = idx & 31;
        int kbl = rem >> 4, p = rem & 15;
        int ks0 = p * 2;
        int r0  = kbl * 32 + ks0;        // local rows r0, r0+1
        f16x2 v2;
        if (cp < 128) {
            v2[0] = (_Float16)(wsh[r0] * tile[r0][cp]);
            v2[1] = (_Float16)(wsh[r0 + 1] * tile[r0 + 1][cp]);
        } else if (cp == 128) {
            v2[0] = (_Float16)wsh[r0];
            v2[1] = (_Float16)wsh[r0 + 1];
        } else {
            v2[0] = (_Float16)0.f;
            v2[1] = (_Float16)0.f;
        }
        *(f16x2*)(hWb + ((size_t)kbl * CP + cp) * 32 + ks0) = v2;
    }
}

// ---------------------------------------------------------------------------
// attn_kernel: pure f16 GEMM out' = A @ hW  (cols 0..127 = numerator,
// col 128 = denominator), then row-normalize.  M=16 per block, grid
// 8×128 = 1024 (4 blocks/CU), 256 thr = 4 waves, each wave: 3 c-tiles
// (2 output tiles + shared w-tile).  A staged via global_load_lds
// double-buffer (1 DMA instr/wave/iter, k-rotated slots); hW read direct
// (1 KB contiguous, L2-resident, XCD-pinned).
// ---------------------------------------------------------------------------
__global__ __launch_bounds__(256, 4) void attn_kernel(const float* __restrict__ A,
                                                      const _Float16* __restrict__ hWt,
                                                      float* __restrict__ out) {
    __shared__ float Alds[2][16 * 64];   // [buf][r][16 slots × 4 words], k-rotated
    __shared__ float den[16];

    int bid = blockIdx.x;
    int b   = bid & 7;                   // XCD-aligned batch
    int i0  = (bid >> 3) << 4;           // 128 row-blocks of 16
    int tid = threadIdx.x;
    int wv  = tid >> 6, l = tid & 63;
    int m   = l & 15, q = l >> 4;

    const float*    Ab  = A   + (size_t)(b * Nn + i0) * Nn;
    const _Float16* hWb = hWt + (size_t)b * NKB * CP * 32;

    // DMA lane mapping: wave wv stages rows wv*4..wv*4+3; lane (q=row-in-4,
    // m=slot): global quad kq = (slot - row) & 15  → LDS slot = (kq + row) & 15
    int sr = wv * 4 + q;
    int skq = (m - sr) & 15;
    const float* sg = Ab + (size_t)sr * Nn + skq * 4;
    float* sl = &Alds[0][0] + wv * 256;  // wave-uniform base (buf added later)

    f32x4 acc[3];
#pragma unroll
    for (int s = 0; s < 3; ++s) acc[s] = (f32x4){0.f, 0.f, 0.f, 0.f};

    // t=0 stage
    dma16(sg, sl);

    for (int t = 0; t < 32; ++t) {
        int buf = t & 1;
        if (t < 31) dma16(sg + (t + 1) * 64, sl + (buf ^ 1) * (16 * 64));
        __syncthreads();                 // drains DMA; tile t (and t+1) ready

        // issue all 6 hW loads up front
        f16x8 bf[6];
#pragma unroll
        for (int ksub = 0; ksub < 2; ++ksub)
#pragma unroll
            for (int s = 0; s < 3; ++s) {
                int ct = (s == 2) ? 8 : wv * 2 + s;
                bf[ksub * 3 + s] = *(const f16x8*)(
                    hWb + ((size_t)(t * 2 + ksub) * CP + ct * 16 + m) * 32 + q * 8);
            }
#pragma unroll
        for (int ksub = 0; ksub < 2; ++ksub) {
            int kq0 = ksub * 8 + 2 * q;
            float4 x = *(const float4*)&Alds[buf][m * 64 + ((kq0 + m) & 15) * 4];
            float4 y = *(const float4*)&Alds[buf][m * 64 + ((kq0 + 1 + m) & 15) * 4];
            union { fp16x2 h2[4]; f16x8 v; } u;
            u.h2[0] = __builtin_amdgcn_cvt_pkrtz(x.x, x.y);
            u.h2[1] = __builtin_amdgcn_cvt_pkrtz(x.z, x.w);
            u.h2[2] = __builtin_amdgcn_cvt_pkrtz(y.x, y.y);
            u.h2[3] = __builtin_amdgcn_cvt_pkrtz(y.z, y.w);
#pragma unroll
            for (int s = 0; s < 3; ++s)
                acc[s] = __builtin_amdgcn_mfma_f32_16x16x32_f16(u.v, bf[ksub * 3 + s],
                                                                acc[s], 0, 0, 0);
        }
        __syncthreads();                 // compute done before buf reuse
    }

    // denominator = w-tile (acc[2]) column 0; D layout: col=lane&15, row=q*4+r
    if (wv == 0 && m == 0) {
#pragma unroll
        for (int r = 0; r < 4; ++r) den[q * 4 + r] = acc[2][r];
    }
    __syncthreads();

#pragma unroll
    for (int r = 0; r < 4; ++r) {
        float invd = 1.f / den[q * 4 + r];
        float* ob = out + (size_t)(b * Nn + i0 + q * 4 + r) * Cn;
#pragma unroll
        for (int s = 0; s < 2; ++s)
            ob[(wv * 2 + s) * 16 + m] = acc[s][r] * invd;
    }
}

// ---------------------------------------------------------------------------
extern "C" void kernel_launch(void* const* d_in, const int* in_sizes, int n_in,
                              void* d_out, int out_size, void* d_ws, size_t ws_size,
                              hipStream_t stream) {
    const float* h  = (const float*)d_in[0];
    const float* A  = (const float*)d_in[1];
    const float* Ww = (const float*)d_in[2];
    const float* Wb = (const float*)d_in[3];
    const float* aw = (const float*)d_in[4];
    // d_in[5] = a_b : cancels in the row normalization, unused
    float* out = (float*)d_out;

    _Float16* hWt = (_Float16*)d_ws;     // 8*64*144*32 f16 = 4.72 MB

    rows_kernel<<<Bn * (Nn / 64), 256, 0, stream>>>(h, Ww, Wb, aw, hWt);
    attn_kernel<<<Bn * (Nn / 16), 256, 0, stream>>>(A, hWt, out);
}

// Round 6
// 242.924 us; speedup vs baseline: 1.0382x; 1.0382x over previous
//
#include <hip/hip_runtime.h>
#include <math.h>
#include <stdint.h>

#define Bn 8
#define Nn 2048
#define Cn 128
#define CP 144          // padded cols: 128 h-cols + w-col(=128) + 15 zero cols
#define NKB (Nn / 32)   // 64 k-blocks of 32

typedef _Float16 f16x8 __attribute__((ext_vector_type(8)));
typedef _Float16 f16x2 __attribute__((ext_vector_type(2)));
typedef __fp16   fp16x2 __attribute__((ext_vector_type(2)));
typedef float    f32x4 __attribute__((ext_vector_type(4)));

__device__ __forceinline__ void dma16(const void* g, void* l) {
    __builtin_amdgcn_global_load_lds((const __attribute__((address_space(1))) uint32_t*)g,
                                     (__attribute__((address_space(3))) uint32_t*)l,
                                     16, 0, 0);
}

// ---------------------------------------------------------------------------
// rows_kernel: per 16-row chunk (4 blocks/CU for latency hiding):
//   v[c] = Ww^T·aw2 (split-d recompute, L2-hot), b2 = Wb·aw2,
//   w = exp(h·v + b2), hWt[b][kb][cp][ks] = f16(w_j * h[j][cp]) (cp<128),
//   f16(w_j) at cp=128, zeros cp 129..143.
// grid = 8 x 128 = 1024 blocks, 256 threads.
// ---------------------------------------------------------------------------
__global__ __launch_bounds__(256) void rows_kernel(const float* __restrict__ h,
                                                   const float* __restrict__ Ww,
                                                   const float* __restrict__ Wb,
                                                   const float* __restrict__ aw,
                                                   _Float16* __restrict__ hWt) {
    __shared__ float tile[16][132];
    __shared__ float vlo[128];
    __shared__ float vhi[128];
    __shared__ float wsh[16];
    __shared__ float b2sh;

    int bid = blockIdx.x;
    int b   = bid & 7;                   // XCD-aligned batch
    int n0  = (bid >> 3) << 4;           // 128 chunks of 16 rows
    int tid = threadIdx.x;

    {   // v halves: tid<128 -> d in [0,64), else [64,128)
        int c = tid & 127, half = tid >> 7;
        float acc = 0.f;
#pragma unroll
        for (int dd = 0; dd < 64; ++dd) {
            int d = half * 64 + dd;
            acc += Ww[d * Cn + c] * aw[Cn + d];
        }
        if (half) vhi[c] = acc; else vlo[c] = acc;
    }
    if (tid < 64) {                      // b2 = Wb·aw2
        float b2p = Wb[tid] * aw[Cn + tid] + Wb[tid + 64] * aw[Cn + tid + 64];
        b2p += __shfl_xor(b2p, 32, 64);
        b2p += __shfl_xor(b2p, 16, 64);
        b2p += __shfl_xor(b2p, 8, 64);
        b2p += __shfl_xor(b2p, 4, 64);
        b2p += __shfl_xor(b2p, 2, 64);
        b2p += __shfl_xor(b2p, 1, 64);
        if (tid == 0) b2sh = b2p;
    }
    {   // stage 16x128 h tile: 512 float4, 2 per thread, coalesced
#pragma unroll
        for (int i = 0; i < 2; ++i) {
            int idx = tid + 256 * i;
            int r = idx >> 5, f4 = idx & 31;
            *(float4*)&tile[r][f4 * 4] =
                ((const float4*)(h + (size_t)(b * Nn + n0 + r) * Cn))[f4];
        }
    }
    __syncthreads();

    {   // dot h·v + exp: 16 threads per row, 8 elems each
        int r = tid >> 4, g = tid & 15;
        float acc = 0.f;
#pragma unroll
        for (int ii = 0; ii < 8; ++ii) {
            int i = g * 8 + ii;
            acc += tile[r][i] * (vlo[i] + vhi[i]);
        }
        acc += __shfl_xor(acc, 1, 64);
        acc += __shfl_xor(acc, 2, 64);
        acc += __shfl_xor(acc, 4, 64);
        acc += __shfl_xor(acc, 8, 64);
        if (g == 0) wsh[r] = expf(acc + b2sh);
    }
    __syncthreads();

    // hWt stores for this 16-ks half-block: 144 cp x 8 pairs = 1152 f16x2
    {
        int kb = n0 >> 5, khalf = (n0 >> 4) & 1;
        _Float16* hWb = hWt + ((size_t)(b * NKB + kb) * CP) * 32 + khalf * 16;
#pragma unroll
        for (int i = 0; i < 5; ++i) {
            int idx = tid + 256 * i;
            if (idx < 1152) {
                int cp = idx >> 3, p = idx & 7;
                int r0 = p * 2;
                f16x2 v2;
                if (cp < 128) {
                    v2[0] = (_Float16)(wsh[r0] * tile[r0][cp]);
                    v2[1] = (_Float16)(wsh[r0 + 1] * tile[r0 + 1][cp]);
                } else if (cp == 128) {
                    v2[0] = (_Float16)wsh[r0];
                    v2[1] = (_Float16)wsh[r0 + 1];
                } else {
                    v2[0] = (_Float16)0.f;
                    v2[1] = (_Float16)0.f;
                }
                *(f16x2*)(hWb + (size_t)cp * 32 + p * 2) = v2;
            }
        }
    }
}

// ---------------------------------------------------------------------------
// attn_kernel: f16 GEMM out' = A @ hW (cols 0..127 numerator, col 128
// denominator), row-normalize epilogue.  M=16/block, grid 8x128=1024
// (4 blocks/CU), 256 thr = 4 waves x (2 own c-tiles + shared w-tile).
// A staged by global_load_lds double-buffer (DMA for t+1 issued AFTER the
// barrier draining t -> overlaps compute).  Per-block k-phase rotation
// koff decorrelates the column window across blocks so concurrent traffic
// spreads over all L2/L3 channels (A rows are 8 KB apart: without this,
// every block hits the same 256-B window -> channel hotspot, ~1.5 TB/s cap).
// ---------------------------------------------------------------------------
__global__ __launch_bounds__(256, 4) void attn_kernel(const float* __restrict__ A,
                                                      const _Float16* __restrict__ hWt,
                                                      float* __restrict__ out) {
    __shared__ float Alds[2][16 * 64];   // [buf][row][16 slots x 4 words], k-rotated
    __shared__ float den[16];

    int bid = blockIdx.x;
    int b   = bid & 7;                   // XCD-aligned batch
    int i0  = (bid >> 3) << 4;
    int koff = ((bid >> 3) * 5 + (bid & 7)) & 31;   // column-phase rotation
    int tid = threadIdx.x;
    int wv  = tid >> 6, l = tid & 63;
    int m   = l & 15, q = l >> 4;

    const float*    Ab  = A   + (size_t)(b * Nn + i0) * Nn;
    const _Float16* hWb = hWt + (size_t)b * NKB * CP * 32;

    // DMA lane mapping: wave wv stages rows wv*4..wv*4+3 (q = row-in-4,
    // m = LDS slot); global quad kq at slot (kq + row) & 15
    int sr  = wv * 4 + q;
    int skq = (m - sr) & 15;
    const float* sg = Ab + (size_t)sr * Nn + skq * 4;
    float* sl = &Alds[0][0] + wv * 256;  // wave-uniform base

    f32x4 acc[3];
#pragma unroll
    for (int s = 0; s < 3; ++s) acc[s] = (f32x4){0.f, 0.f, 0.f, 0.f};

    dma16(sg + (size_t)koff * 64, sl);   // stage logical tile 0

    for (int t = 0; t < 32; ++t) {
        int buf = t & 1;
        __syncthreads();                 // drains tile t's DMA; syncs buf reuse
        if (t < 31)                      // t+1 flies during compute of t
            dma16(sg + (size_t)((t + 1 + koff) & 31) * 64,
                  sl + (buf ^ 1) * (16 * 64));

        int kb = (t + koff) & 31;        // logical 64-float k-block
        // issue all 6 hW loads up front (1 KB contiguous each)
        f16x8 bf[6];
#pragma unroll
        for (int ksub = 0; ksub < 2; ++ksub)
#pragma unroll
            for (int s = 0; s < 3; ++s) {
                int ct = (s == 2) ? 8 : wv * 2 + s;
                bf[ksub * 3 + s] = *(const f16x8*)(
                    hWb + ((size_t)(kb * 2 + ksub) * CP + ct * 16 + m) * 32 + q * 8);
            }
#pragma unroll
        for (int ksub = 0; ksub < 2; ++ksub) {
            int kq0 = ksub * 8 + 2 * q;
            float4 x = *(const float4*)&Alds[buf][m * 64 + ((kq0 + m) & 15) * 4];
            float4 y = *(const float4*)&Alds[buf][m * 64 + ((kq0 + 1 + m) & 15) * 4];
            union { fp16x2 h2[4]; f16x8 v; } u;
            u.h2[0] = __builtin_amdgcn_cvt_pkrtz(x.x, x.y);
            u.h2[1] = __builtin_amdgcn_cvt_pkrtz(x.z, x.w);
            u.h2[2] = __builtin_amdgcn_cvt_pkrtz(y.x, y.y);
            u.h2[3] = __builtin_amdgcn_cvt_pkrtz(y.z, y.w);
#pragma unroll
            for (int s = 0; s < 3; ++s)
                acc[s] = __builtin_amdgcn_mfma_f32_16x16x32_f16(u.v, bf[ksub * 3 + s],
                                                                acc[s], 0, 0, 0);
        }
    }

    // denominator = w-tile (acc[2]) column 0; D layout: col=lane&15, row=q*4+r
    if (wv == 0 && m == 0) {
#pragma unroll
        for (int r = 0; r < 4; ++r) den[q * 4 + r] = acc[2][r];
    }
    __syncthreads();

#pragma unroll
    for (int r = 0; r < 4; ++r) {
        float invd = 1.f / den[q * 4 + r];
        float* ob = out + (size_t)(b * Nn + i0 + q * 4 + r) * Cn;
#pragma unroll
        for (int s = 0; s < 2; ++s)
            ob[(wv * 2 + s) * 16 + m] = acc[s][r] * invd;
    }
}

// ---------------------------------------------------------------------------
extern "C" void kernel_launch(void* const* d_in, const int* in_sizes, int n_in,
                              void* d_out, int out_size, void* d_ws, size_t ws_size,
                              hipStream_t stream) {
    const float* h  = (const float*)d_in[0];
    const float* A  = (const float*)d_in[1];
    const float* Ww = (const float*)d_in[2];
    const float* Wb = (const float*)d_in[3];
    const float* aw = (const float*)d_in[4];
    // d_in[5] = a_b : cancels in the row normalization, unused
    float* out = (float*)d_out;

    _Float16* hWt = (_Float16*)d_ws;     // 8*64*144*32 f16 = 4.72 MB

    rows_kernel<<<Bn * (Nn / 16), 256, 0, stream>>>(h, Ww, Wb, aw, hWt);
    attn_kernel<<<Bn * (Nn / 16), 256, 0, stream>>>(A, hWt, out);
}

// Round 7
// 225.998 us; speedup vs baseline: 1.1159x; 1.0749x over previous
//
#include <hip/hip_runtime.h>
#include <math.h>
#include <stdint.h>

#define Bn 8
#define Nn 2048
#define Cn 128
#define CP 144          // padded cols: 128 h-cols + w-col(=128) + 15 zero cols
#define NKB (Nn / 32)   // 64 k-blocks of 32

typedef _Float16 f16x8 __attribute__((ext_vector_type(8)));
typedef _Float16 f16x4 __attribute__((ext_vector_type(4)));
typedef _Float16 f16x2 __attribute__((ext_vector_type(2)));
typedef __fp16   fp16x2 __attribute__((ext_vector_type(2)));
typedef float    f32x4 __attribute__((ext_vector_type(4)));

// ---------------------------------------------------------------------------
// rows_kernel (unchanged from R6): per 16-row chunk:
//   v[c]=Ww^T·aw2, b2=Wb·aw2, w=exp(h·v+b2),
//   hWt[b][kb][cp][ks] = f16(w_j*h[j][cp]) (cp<128), f16(w_j) at cp=128,
//   zeros cp 129..143.   grid = 8 x 128 = 1024 blocks, 256 threads.
// ---------------------------------------------------------------------------
__global__ __launch_bounds__(256) void rows_kernel(const float* __restrict__ h,
                                                   const float* __restrict__ Ww,
                                                   const float* __restrict__ Wb,
                                                   const float* __restrict__ aw,
                                                   _Float16* __restrict__ hWt) {
    __shared__ float tile[16][132];
    __shared__ float vlo[128];
    __shared__ float vhi[128];
    __shared__ float wsh[16];
    __shared__ float b2sh;

    int bid = blockIdx.x;
    int b   = bid & 7;
    int n0  = (bid >> 3) << 4;
    int tid = threadIdx.x;

    {   // v halves
        int c = tid & 127, half = tid >> 7;
        float acc = 0.f;
#pragma unroll
        for (int dd = 0; dd < 64; ++dd) {
            int d = half * 64 + dd;
            acc += Ww[d * Cn + c] * aw[Cn + d];
        }
        if (half) vhi[c] = acc; else vlo[c] = acc;
    }
    if (tid < 64) {
        float b2p = Wb[tid] * aw[Cn + tid] + Wb[tid + 64] * aw[Cn + tid + 64];
        b2p += __shfl_xor(b2p, 32, 64);
        b2p += __shfl_xor(b2p, 16, 64);
        b2p += __shfl_xor(b2p, 8, 64);
        b2p += __shfl_xor(b2p, 4, 64);
        b2p += __shfl_xor(b2p, 2, 64);
        b2p += __shfl_xor(b2p, 1, 64);
        if (tid == 0) b2sh = b2p;
    }
    {   // stage 16x128 h tile
#pragma unroll
        for (int i = 0; i < 2; ++i) {
            int idx = tid + 256 * i;
            int r = idx >> 5, f4 = idx & 31;
            *(float4*)&tile[r][f4 * 4] =
                ((const float4*)(h + (size_t)(b * Nn + n0 + r) * Cn))[f4];
        }
    }
    __syncthreads();

    {   // w = exp(h·v + b2)
        int r = tid >> 4, g = tid & 15;
        float acc = 0.f;
#pragma unroll
        for (int ii = 0; ii < 8; ++ii) {
            int i = g * 8 + ii;
            acc += tile[r][i] * (vlo[i] + vhi[i]);
        }
        acc += __shfl_xor(acc, 1, 64);
        acc += __shfl_xor(acc, 2, 64);
        acc += __shfl_xor(acc, 4, 64);
        acc += __shfl_xor(acc, 8, 64);
        if (g == 0) wsh[r] = expf(acc + b2sh);
    }
    __syncthreads();

    {   // hWt stores: 144 cp x 8 pairs = 1152 f16x2
        int kb = n0 >> 5, khalf = (n0 >> 4) & 1;
        _Float16* hWb = hWt + ((size_t)(b * NKB + kb) * CP) * 32 + khalf * 16;
#pragma unroll
        for (int i = 0; i < 5; ++i) {
            int idx = tid + 256 * i;
            if (idx < 1152) {
                int cp = idx >> 3, p = idx & 7;
                int r0 = p * 2;
                f16x2 v2;
                if (cp < 128) {
                    v2[0] = (_Float16)(wsh[r0] * tile[r0][cp]);
                    v2[1] = (_Float16)(wsh[r0 + 1] * tile[r0 + 1][cp]);
                } else if (cp == 128) {
                    v2[0] = (_Float16)wsh[r0];
                    v2[1] = (_Float16)wsh[r0 + 1];
                } else {
                    v2[0] = (_Float16)0.f;
                    v2[1] = (_Float16)0.f;
                }
                *(f16x2*)(hWb + (size_t)cp * 32 + p * 2) = v2;
            }
        }
    }
}

// ---------------------------------------------------------------------------
// attn_kernel: f16 GEMM out' = A @ hW (cols 0..127 numerator, col 128
// denominator via MFMA), row-normalize epilogue.
// M=32/block, grid 8x64=512 (2 blocks/CU), 512 thr = 8 waves.
// Wave w owns c-tile w (cols w*16..+15); waves 0/1 also own the den tile
// (cp 128..143) for m-tile 0/1.  Per iter: 64 k's (2 chunks of 32).
// A staged f32->f16 in LDS, double-buffered, 1 barrier/iter; B-frags from
// global (L2) with 1-iter register prefetch; A-globals 2-iter prefetch.
// Manual 2x unroll gives the prefetch buffers distinct names.
// ---------------------------------------------------------------------------
__global__ __launch_bounds__(512, 4) void attn_kernel(const float* __restrict__ A,
                                                      const _Float16* __restrict__ hWt,
                                                      float* __restrict__ out) {
    __shared__ _Float16 Af[2][2][32][40];   // [buf][chunk][row][kpad40] f16
    __shared__ float den[32];

    int bid = blockIdx.x;
    int b   = bid & 7;                      // XCD-aligned batch
    int i0  = (bid >> 3) << 5;              // 64 row-blocks of 32
    int tid = threadIdx.x;
    int wv  = tid >> 6, l = tid & 63;
    int m   = l & 15, q = l >> 4;

    const float*    Ab  = A   + (size_t)(b * Nn + i0) * Nn;
    const _Float16* hWb = hWt + (size_t)b * NKB * CP * 32;

    // staging map: thread -> (row, float4-slot); 16 thr x 64 B per row
    int sr = tid >> 4, sf4 = tid & 15;
    const float* sg = Ab + (size_t)sr * Nn + sf4 * 4;
    int sch = sf4 >> 3, skl = (sf4 & 7) * 4;

    f32x4 accc[2];                          // own c-tile, m-tiles 0/1
    f32x4 acc8;                             // den tile (waves 0,1 only)
    accc[0] = (f32x4){0.f, 0.f, 0.f, 0.f};
    accc[1] = (f32x4){0.f, 0.f, 0.f, 0.f};
    acc8    = (f32x4){0.f, 0.f, 0.f, 0.f};

    auto loadA = [&](int t) { return *(const float4*)(sg + t * 64); };
    auto storeA = [&](int t, float4 v) {
        union { fp16x2 h2[2]; f16x4 v4; } u;
        u.h2[0] = __builtin_amdgcn_cvt_pkrtz(v.x, v.y);
        u.h2[1] = __builtin_amdgcn_cvt_pkrtz(v.z, v.w);
        *(f16x4*)&Af[t & 1][sch][sr][skl] = u.v4;
    };
    auto loadB = [&](int t, f16x8* bf) {    // bf[0..1]=own c (ck 0,1); bf[2..3]=den tile
#pragma unroll
        for (int ck = 0; ck < 2; ++ck)
            bf[ck] = *(const f16x8*)(hWb + ((size_t)(2 * t + ck) * CP + wv * 16 + m) * 32 + q * 8);
        if (wv < 2) {
#pragma unroll
            for (int ck = 0; ck < 2; ++ck)
                bf[2 + ck] = *(const f16x8*)(hWb + ((size_t)(2 * t + ck) * CP + 128 + m) * 32 + q * 8);
        }
    };
    auto compute = [&](int buf, const f16x8* bf) {
#pragma unroll
        for (int ck = 0; ck < 2; ++ck) {
            f16x8 af0 = *(const f16x8*)&Af[buf][ck][m][q * 8];        // m-tile 0
            f16x8 af1 = *(const f16x8*)&Af[buf][ck][16 + m][q * 8];   // m-tile 1
            accc[0] = __builtin_amdgcn_mfma_f32_16x16x32_f16(af0, bf[ck], accc[0], 0, 0, 0);
            accc[1] = __builtin_amdgcn_mfma_f32_16x16x32_f16(af1, bf[ck], accc[1], 0, 0, 0);
            if (wv < 2)
                acc8 = __builtin_amdgcn_mfma_f32_16x16x32_f16(wv ? af1 : af0, bf[2 + ck],
                                                              acc8, 0, 0, 0);
        }
    };

    // preamble: A(0),A(1) in regs; B(0) in bfA; buf0 <- A(0)
    float4 a0 = loadA(0);
    float4 a1 = loadA(1);
    f16x8 bfA[4], bfB[4];
    loadB(0, bfA);
    storeA(0, a0);
    __syncthreads();

    for (int t2 = 0; t2 < 16; ++t2) {
        int te = 2 * t2, to = te + 1;
        // iter te (even, buf0, frags bfA)
        loadB(to, bfB);
        if (t2 < 15) a0 = loadA(te + 2);
        compute(0, bfA);
        storeA(to, a1);                     // buf1 <- A(te+1)
        __syncthreads();
        // iter to (odd, buf1, frags bfB)
        if (t2 < 15) {
            loadB(to + 1, bfA);
            a1 = loadA(to + 2);
        }
        compute(1, bfB);
        if (t2 < 15) storeA(to + 1, a0);    // buf0 <- A(te+2)
        __syncthreads();
    }

    // denominator: D col 0 of den tile = cp 128 = w-column
    if (wv < 2 && m == 0) {
#pragma unroll
        for (int r = 0; r < 4; ++r) den[wv * 16 + q * 4 + r] = acc8[r];
    }
    __syncthreads();

#pragma unroll
    for (int mt = 0; mt < 2; ++mt) {
#pragma unroll
        for (int r = 0; r < 4; ++r) {
            int row = mt * 16 + q * 4 + r;
            float invd = 1.f / den[row];
            out[(size_t)(b * Nn + i0 + row) * Cn + wv * 16 + m] = accc[mt][r] * invd;
        }
    }
}

// ---------------------------------------------------------------------------
extern "C" void kernel_launch(void* const* d_in, const int* in_sizes, int n_in,
                              void* d_out, int out_size, void* d_ws, size_t ws_size,
                              hipStream_t stream) {
    const float* h  = (const float*)d_in[0];
    const float* A  = (const float*)d_in[1];
    const float* Ww = (const float*)d_in[2];
    const float* Wb = (const float*)d_in[3];
    const float* aw = (const float*)d_in[4];
    // d_in[5] = a_b : cancels in the row normalization, unused
    float* out = (float*)d_out;

    _Float16* hWt = (_Float16*)d_ws;        // 8*64*144*32 f16 = 4.72 MB

    rows_kernel<<<Bn * (Nn / 16), 256, 0, stream>>>(h, Ww, Wb, aw, hWt);
    attn_kernel<<<Bn * (Nn / 32), 512, 0, stream>>>(A, hWt, out);
}